// Round 12
// baseline (18.258 us; speedup 1.0000x reference)
//
#include <hip/hip_runtime.h>
#include <math.h>

#define Bn 4
#define Pn 24
#define Gn 24
#define Hd 512
#define Wd 512
#define NOBJ (Bn * Pn)
#define SPLIT 2
#define BLKT 1024
#define NWAVE (BLKT / 64)
#define IOU_THRESH 0.5f

// ws layout:
//   acc float[NOBJ][SPLIT][4]  (bce_sum, inter, sum_p, sum_t)  -- every block
//     writes its slot unconditionally -> no zero-init, no atomics.
//   aux float[NOBJ][2]         (keep, cnt), written by part-0 block so the
//     finalize kernel needn't recompute the match.
// Structure notes (measured):
//  - rounds 3/9/10: any in-kernel cross-XCD reduction tail (fences, tickets,
//    hierarchical atomics) costs MORE than a kernel-node boundary on gfx950.
//  - round 12: 192x1024 instead of 768x256 keeps per-thread work identical
//    (step = SPLIT*BLKT = 2048 unchanged) but cuts block generations per CU
//    from ~3 to 1, removing repeated prologue latency (box loads -> IoU chain
//    -> cold mask loads) from the critical path.
#define AUX_OFF (NOBJ * SPLIT * 4)

__device__ __forceinline__ void match_obj(const float* __restrict__ pred_boxes,
                                          const float* __restrict__ gt_boxes,
                                          const int* __restrict__ pred_valid,
                                          const int* __restrict__ gt_valid,
                                          int obj, int& keep, int& gidx,
                                          int& y1, int& x1, int& y2, int& x2) {
    int b = obj / Pn;
    const float* pb = pred_boxes + (size_t)obj * 4;
    float a0 = pb[0], a1 = pb[1], a2 = pb[2], a3 = pb[3];
    float area_a = (a2 - a0) * (a3 - a1);
    float best = -1.0f;
    gidx = 0;
    #pragma unroll
    for (int g = 0; g < Gn; ++g) {
        const float* gb = gt_boxes + ((size_t)b * Gn + g) * 4;
        float b0 = gb[0], b1 = gb[1], b2 = gb[2], b3 = gb[3];
        float area_b = (b2 - b0) * (b3 - b1);
        float ih = fmaxf(fminf(a2, b2) - fmaxf(a0, b0), 0.0f);
        float iw = fmaxf(fminf(a3, b3) - fmaxf(a1, b1), 0.0f);
        float inter = ih * iw;
        float uni = area_a + area_b - inter;
        float iou = (uni == 0.0f) ? 0.0f : inter / uni;
        if (gt_valid[b * Gn + g] == 0) iou = -1.0f;
        if (iou > best) { best = iou; gidx = g; }  // first-max == jnp.argmax
    }
    keep = (best >= IOU_THRESH) && (pred_valid[obj] != 0);
    // jnp.round is round-half-to-even -> rintf (default FE_TONEAREST)
    y1 = max(0, (int)rintf(a0 * (float)Hd));
    x1 = max(0, (int)rintf(a1 * (float)Wd));
    y2 = min((int)rintf(a2 * (float)Hd), Hd - 1);
    x2 = min((int)rintf(a3 * (float)Wd), Wd - 1);
}

__global__ __launch_bounds__(BLKT) void region_kernel(
    const float* __restrict__ pred_masks, const float* __restrict__ gt_masks,
    const float* __restrict__ pred_boxes, const float* __restrict__ gt_boxes,
    const int* __restrict__ pred_valid, const int* __restrict__ gt_valid,
    float* __restrict__ acc, float* __restrict__ aux) {
    int obj = blockIdx.x;   // b*Pn + p
    int part = blockIdx.y;  // 0..SPLIT-1

    int keep, gidx, y1, x1, y2, x2;
    match_obj(pred_boxes, gt_boxes, pred_valid, gt_valid, obj, keep, gidx, y1, x1, y2, x2);

    float v0 = 0.0f, v1 = 0.0f, v2 = 0.0f, v3 = 0.0f;
    if (keep && y2 >= y1 && x2 >= x1) {
        int Wr = x2 - x1 + 1;
        int Hr = y2 - y1 + 1;
        int x1a = x1 & ~3;                    // 16B-aligned start column
        int W4 = (x2 >> 2) - (x1 >> 2) + 1;   // aligned 4-px groups covering [x1,x2]
        int N4 = Hr * W4;
        int idx = part * BLKT + (int)threadIdx.x;
        if (idx < N4) {
            const float* pm = pred_masks + (size_t)obj * Hd * Wd + x1a;
            const float* gm = gt_masks + ((size_t)(obj / Pn) * Gn + gidx) * Hd * Wd + x1a;
            const int step = SPLIT * BLKT;    // groups advanced per sweep (=2048, unchanged)
            int r = idx / W4;                 // one div per thread
            int c = idx - r * W4;
            int dr = step / W4;               // one more div per thread
            int dc = step - dr * W4;
            int rel0 = x1a - x1;              // -3..0

            // depth-1 software pipeline: loads of iteration i+1 issue before
            // the log-chain of iteration i (addresses stride-incremental).
            int off = (y1 + r) * Wd + (c << 2);
            float4 p4 = *reinterpret_cast<const float4*>(pm + off);
            float4 q4 = *reinterpret_cast<const float4*>(gm + off);
            int rel = rel0 + (c << 2);
            while (true) {
                idx += step;
                bool more = idx < N4;
                float4 p4n, q4n;
                int reln = 0;
                if (more) {
                    c += dc; r += dr;
                    if (c >= W4) { c -= W4; ++r; }
                    int offn = (y1 + r) * Wd + (c << 2);
                    p4n = *reinterpret_cast<const float4*>(pm + offn);
                    q4n = *reinterpret_cast<const float4*>(gm + offn);
                    reln = rel0 + (c << 2);
                }
                bool m0 = (unsigned)(rel + 0) < (unsigned)Wr;
                bool m1 = (unsigned)(rel + 1) < (unsigned)Wr;
                bool m2 = (unsigned)(rel + 2) < (unsigned)Wr;
                bool m3 = (unsigned)(rel + 3) < (unsigned)Wr;
                float p0 = m0 ? p4.x : 0.0f, q0 = m0 ? q4.x : 0.0f;
                float p1 = m1 ? p4.y : 0.0f, q1 = m1 ? q4.y : 0.0f;
                float p2 = m2 ? p4.z : 0.0f, q2 = m2 ? q4.z : 0.0f;
                float p3 = m3 ? p4.w : 0.0f, q3 = m3 ? q4.w : 0.0f;
                // t exactly 0/1; masked pixel -> p=q=0 -> arg = 1 (log adds 0).
                // p in [1e-4, 1-1e-4] => -100 clamp provably inactive; 4-arg
                // product >= 1e-16 >> FLT_MIN: sum(log) == log(prod),
                // ONE transcendental per group.
                float a0 = (q0 > 0.5f) ? p0 : 1.0f - p0;
                float a1 = (q1 > 0.5f) ? p1 : 1.0f - p1;
                float a2 = (q2 > 0.5f) ? p2 : 1.0f - p2;
                float a3 = (q3 > 0.5f) ? p3 : 1.0f - p3;
                v0 -= __logf((a0 * a1) * (a2 * a3));
                v1 = fmaf(p0, q0, fmaf(p1, q1, fmaf(p2, q2, fmaf(p3, q3, v1))));
                v2 += (p0 + p1) + (p2 + p3);
                v3 += (q0 + q1) + (q2 + q3);
                if (!more) break;
                p4 = p4n; q4 = q4n; rel = reln;
            }
        }
    }

    // block reduce 1024 -> 4 sums (16 waves)
    for (int o = 32; o > 0; o >>= 1) {
        v0 += __shfl_down(v0, o, 64);
        v1 += __shfl_down(v1, o, 64);
        v2 += __shfl_down(v2, o, 64);
        v3 += __shfl_down(v3, o, 64);
    }
    __shared__ float red[NWAVE][4];
    int lane = threadIdx.x & 63, w = threadIdx.x >> 6;
    if (lane == 0) { red[w][0] = v0; red[w][1] = v1; red[w][2] = v2; red[w][3] = v3; }
    __syncthreads();
    if (threadIdx.x < 4) {
        float sfin = 0.0f;
        #pragma unroll
        for (int k = 0; k < NWAVE; ++k) sfin += red[k][threadIdx.x];
        acc[((size_t)obj * SPLIT + part) * 4 + threadIdx.x] = sfin;  // unconditional slot write
    } else if (part == 0 && threadIdx.x == 4) {
        float cnt = (y2 >= y1 && x2 >= x1)
                      ? (float)((y2 - y1 + 1) * (x2 - x1 + 1)) : 0.0f;
        aux[obj * 2 + 0] = keep ? 1.0f : 0.0f;
        aux[obj * 2 + 1] = cnt;
    }
}

__global__ __launch_bounds__(128) void finalize_kernel(
    const float* __restrict__ acc, const float* __restrict__ aux,
    float* __restrict__ out) {
    int i = threadIdx.x;  // 128 threads, 2 waves
    float loss = 0.0f, nk = 0.0f;
    if (i < NOBJ) {
        // hoist all loads unconditionally so L2 latency overlaps the branch
        const float4* a = reinterpret_cast<const float4*>(acc) + (size_t)i * SPLIT;
        float4 q0 = a[0], q1 = a[1];
        float2 ax = reinterpret_cast<const float2*>(aux)[i];  // (keep, cnt)
        float s0 = q0.x + q1.x;
        float s1 = q0.y + q1.y;
        float s2 = q0.z + q1.z;
        float s3 = q0.w + q1.w;
        if (ax.x > 0.5f) {
            nk = 1.0f;
            float bce = s0 / fmaxf(ax.y, 1.0f);
            float dice = 1.0f - (2.0f * s1 + 1.0f) / (s2 + s3 + 1.0f);
            loss = bce + dice;
        }
    }
    float v0 = loss, v1 = nk;
    for (int o = 32; o > 0; o >>= 1) {
        v0 += __shfl_down(v0, o, 64);
        v1 += __shfl_down(v1, o, 64);
    }
    __shared__ float red[2][2];
    if ((threadIdx.x & 63) == 0) { red[threadIdx.x >> 6][0] = v0; red[threadIdx.x >> 6][1] = v1; }
    __syncthreads();
    if (threadIdx.x == 0) {
        float total = red[0][0] + red[1][0];
        float nobj = red[0][1] + red[1][1];
        out[0] = total / fmaxf(nobj, 1.0f);
    }
}

extern "C" void kernel_launch(void* const* d_in, const int* in_sizes, int n_in,
                              void* d_out, int out_size, void* d_ws, size_t ws_size,
                              hipStream_t stream) {
    const float* pred_masks = (const float*)d_in[0];
    const float* pred_boxes = (const float*)d_in[1];
    const float* gt_boxes   = (const float*)d_in[2];
    const float* gt_masks   = (const float*)d_in[3];
    const int*   pred_valid = (const int*)d_in[4];
    const int*   gt_valid   = (const int*)d_in[5];
    float* out = (float*)d_out;
    float* acc = (float*)d_ws;       // [NOBJ][SPLIT][4]
    float* aux = acc + AUX_OFF;      // [NOBJ][2]

    region_kernel<<<dim3(NOBJ, SPLIT), BLKT, 0, stream>>>(
        pred_masks, gt_masks, pred_boxes, gt_boxes, pred_valid, gt_valid, acc, aux);
    finalize_kernel<<<1, 128, 0, stream>>>(acc, aux, out);
}

// Round 13
// 15.782 us; speedup vs baseline: 1.1569x; 1.1569x over previous
//
#include <hip/hip_runtime.h>
#include <math.h>

#define Bn 4
#define Pn 24
#define Gn 24
#define Hd 512
#define Wd 512
#define NOBJ (Bn * Pn)
#define SPLIT 8
#define IOU_THRESH 0.5f

// ws layout:
//   acc float[NOBJ][SPLIT][4]  (bce_sum, inter, sum_p, sum_t)  -- every block
//     writes its slot unconditionally -> no zero-init, no atomics.
//   aux float[NOBJ][2]         (keep, cnt), written by part-0 block so the
//     finalize kernel needn't recompute the match.
//
// Structure notes (all measured this session):
//  - rounds 3/9/10: ANY in-kernel cross-XCD reduction tail (threadfence,
//    flat ticket counter, hierarchical tickets) costs +4..+12us vs a kernel
//    boundary on gfx950. Two kernel nodes is the optimal structure.
//  - rounds 6/12: grid geometry 768x256 (SPLIT=8) beats 1536x256 (per-block
//    fixed cost) and 192x1024 (block-retire tail amplification).
//  - round 8: pipeline depth > 1 is neutral; depth-1 prefetch (here) is the
//    sweet spot.
#define AUX_OFF (NOBJ * SPLIT * 4)

__device__ __forceinline__ void match_obj(const float* __restrict__ pred_boxes,
                                          const float* __restrict__ gt_boxes,
                                          const int* __restrict__ pred_valid,
                                          const int* __restrict__ gt_valid,
                                          int obj, int& keep, int& gidx,
                                          int& y1, int& x1, int& y2, int& x2) {
    int b = obj / Pn;
    const float* pb = pred_boxes + (size_t)obj * 4;
    float a0 = pb[0], a1 = pb[1], a2 = pb[2], a3 = pb[3];
    float area_a = (a2 - a0) * (a3 - a1);
    float best = -1.0f;
    gidx = 0;
    #pragma unroll
    for (int g = 0; g < Gn; ++g) {
        const float* gb = gt_boxes + ((size_t)b * Gn + g) * 4;
        float b0 = gb[0], b1 = gb[1], b2 = gb[2], b3 = gb[3];
        float area_b = (b2 - b0) * (b3 - b1);
        float ih = fmaxf(fminf(a2, b2) - fmaxf(a0, b0), 0.0f);
        float iw = fmaxf(fminf(a3, b3) - fmaxf(a1, b1), 0.0f);
        float inter = ih * iw;
        float uni = area_a + area_b - inter;
        float iou = (uni == 0.0f) ? 0.0f : inter / uni;
        if (gt_valid[b * Gn + g] == 0) iou = -1.0f;
        if (iou > best) { best = iou; gidx = g; }  // first-max == jnp.argmax
    }
    keep = (best >= IOU_THRESH) && (pred_valid[obj] != 0);
    // jnp.round is round-half-to-even -> rintf (default FE_TONEAREST)
    y1 = max(0, (int)rintf(a0 * (float)Hd));
    x1 = max(0, (int)rintf(a1 * (float)Wd));
    y2 = min((int)rintf(a2 * (float)Hd), Hd - 1);
    x2 = min((int)rintf(a3 * (float)Wd), Wd - 1);
}

__global__ __launch_bounds__(256) void region_kernel(
    const float* __restrict__ pred_masks, const float* __restrict__ gt_masks,
    const float* __restrict__ pred_boxes, const float* __restrict__ gt_boxes,
    const int* __restrict__ pred_valid, const int* __restrict__ gt_valid,
    float* __restrict__ acc, float* __restrict__ aux) {
    int obj = blockIdx.x;   // b*Pn + p
    int part = blockIdx.y;  // 0..SPLIT-1

    int keep, gidx, y1, x1, y2, x2;
    match_obj(pred_boxes, gt_boxes, pred_valid, gt_valid, obj, keep, gidx, y1, x1, y2, x2);

    float v0 = 0.0f, v1 = 0.0f, v2 = 0.0f, v3 = 0.0f;
    if (keep && y2 >= y1 && x2 >= x1) {
        int Wr = x2 - x1 + 1;
        int Hr = y2 - y1 + 1;
        int x1a = x1 & ~3;                    // 16B-aligned start column
        int W4 = (x2 >> 2) - (x1 >> 2) + 1;   // aligned 4-px groups covering [x1,x2]
        int N4 = Hr * W4;
        int idx = part * 256 + (int)threadIdx.x;
        if (idx < N4) {
            const float* pm = pred_masks + (size_t)obj * Hd * Wd + x1a;
            const float* gm = gt_masks + ((size_t)(obj / Pn) * Gn + gidx) * Hd * Wd + x1a;
            const int step = SPLIT * 256;     // groups advanced per sweep
            int r = idx / W4;                 // one div per thread
            int c = idx - r * W4;
            int dr = step / W4;               // one more div per thread
            int dc = step - dr * W4;
            int rel0 = x1a - x1;              // -3..0

            // depth-1 software pipeline: loads of iteration i+1 issue before
            // the log-chain of iteration i (addresses stride-incremental).
            int off = (y1 + r) * Wd + (c << 2);
            float4 p4 = *reinterpret_cast<const float4*>(pm + off);
            float4 q4 = *reinterpret_cast<const float4*>(gm + off);
            int rel = rel0 + (c << 2);
            while (true) {
                idx += step;
                bool more = idx < N4;
                float4 p4n, q4n;
                int reln = 0;
                if (more) {
                    c += dc; r += dr;
                    if (c >= W4) { c -= W4; ++r; }
                    int offn = (y1 + r) * Wd + (c << 2);
                    p4n = *reinterpret_cast<const float4*>(pm + offn);
                    q4n = *reinterpret_cast<const float4*>(gm + offn);
                    reln = rel0 + (c << 2);
                }
                bool m0 = (unsigned)(rel + 0) < (unsigned)Wr;
                bool m1 = (unsigned)(rel + 1) < (unsigned)Wr;
                bool m2 = (unsigned)(rel + 2) < (unsigned)Wr;
                bool m3 = (unsigned)(rel + 3) < (unsigned)Wr;
                float p0 = m0 ? p4.x : 0.0f, q0 = m0 ? q4.x : 0.0f;
                float p1 = m1 ? p4.y : 0.0f, q1 = m1 ? q4.y : 0.0f;
                float p2 = m2 ? p4.z : 0.0f, q2 = m2 ? q4.z : 0.0f;
                float p3 = m3 ? p4.w : 0.0f, q3 = m3 ? q4.w : 0.0f;
                // t exactly 0/1; masked pixel -> p=q=0 -> arg = 1 (log adds 0).
                // p in [1e-4, 1-1e-4] => -100 clamp provably inactive; 4-arg
                // product >= 1e-16 >> FLT_MIN: sum(log) == log(prod),
                // ONE transcendental per group.
                float a0 = (q0 > 0.5f) ? p0 : 1.0f - p0;
                float a1 = (q1 > 0.5f) ? p1 : 1.0f - p1;
                float a2 = (q2 > 0.5f) ? p2 : 1.0f - p2;
                float a3 = (q3 > 0.5f) ? p3 : 1.0f - p3;
                v0 -= __logf((a0 * a1) * (a2 * a3));
                v1 = fmaf(p0, q0, fmaf(p1, q1, fmaf(p2, q2, fmaf(p3, q3, v1))));
                v2 += (p0 + p1) + (p2 + p3);
                v3 += (q0 + q1) + (q2 + q3);
                if (!more) break;
                p4 = p4n; q4 = q4n; rel = reln;
            }
        }
    }

    // block reduce 256 -> 4 sums
    for (int o = 32; o > 0; o >>= 1) {
        v0 += __shfl_down(v0, o, 64);
        v1 += __shfl_down(v1, o, 64);
        v2 += __shfl_down(v2, o, 64);
        v3 += __shfl_down(v3, o, 64);
    }
    __shared__ float red[4][4];
    int lane = threadIdx.x & 63, w = threadIdx.x >> 6;
    if (lane == 0) { red[w][0] = v0; red[w][1] = v1; red[w][2] = v2; red[w][3] = v3; }
    __syncthreads();
    if (threadIdx.x < 4) {
        float sfin = red[0][threadIdx.x] + red[1][threadIdx.x] +
                     red[2][threadIdx.x] + red[3][threadIdx.x];
        acc[((size_t)obj * SPLIT + part) * 4 + threadIdx.x] = sfin;  // unconditional slot write
    } else if (part == 0 && threadIdx.x == 4) {
        float cnt = (y2 >= y1 && x2 >= x1)
                      ? (float)((y2 - y1 + 1) * (x2 - x1 + 1)) : 0.0f;
        aux[obj * 2 + 0] = keep ? 1.0f : 0.0f;
        aux[obj * 2 + 1] = cnt;
    }
}

__global__ __launch_bounds__(128) void finalize_kernel(
    const float* __restrict__ acc, const float* __restrict__ aux,
    float* __restrict__ out) {
    int i = threadIdx.x;  // 128 threads, 2 waves
    float loss = 0.0f, nk = 0.0f;
    if (i < NOBJ) {
        float keepf = aux[i * 2 + 0];
        float cnt = aux[i * 2 + 1];
        if (keepf > 0.5f) {
            nk = 1.0f;
            const float4* a = reinterpret_cast<const float4*>(acc) + (size_t)i * SPLIT;
            float s0 = 0.0f, s1 = 0.0f, s2 = 0.0f, s3 = 0.0f;
            #pragma unroll
            for (int p = 0; p < SPLIT; ++p) {
                float4 v = a[p];
                s0 += v.x; s1 += v.y; s2 += v.z; s3 += v.w;
            }
            float bce = s0 / fmaxf(cnt, 1.0f);
            float dice = 1.0f - (2.0f * s1 + 1.0f) / (s2 + s3 + 1.0f);
            loss = bce + dice;
        }
    }
    float v0 = loss, v1 = nk;
    for (int o = 32; o > 0; o >>= 1) {
        v0 += __shfl_down(v0, o, 64);
        v1 += __shfl_down(v1, o, 64);
    }
    __shared__ float red[2][2];
    if ((threadIdx.x & 63) == 0) { red[threadIdx.x >> 6][0] = v0; red[threadIdx.x >> 6][1] = v1; }
    __syncthreads();
    if (threadIdx.x == 0) {
        float total = red[0][0] + red[1][0];
        float nobj = red[0][1] + red[1][1];
        out[0] = total / fmaxf(nobj, 1.0f);
    }
}

extern "C" void kernel_launch(void* const* d_in, const int* in_sizes, int n_in,
                              void* d_out, int out_size, void* d_ws, size_t ws_size,
                              hipStream_t stream) {
    const float* pred_masks = (const float*)d_in[0];
    const float* pred_boxes = (const float*)d_in[1];
    const float* gt_boxes   = (const float*)d_in[2];
    const float* gt_masks   = (const float*)d_in[3];
    const int*   pred_valid = (const int*)d_in[4];
    const int*   gt_valid   = (const int*)d_in[5];
    float* out = (float*)d_out;
    float* acc = (float*)d_ws;       // [NOBJ][SPLIT][4]
    float* aux = acc + AUX_OFF;      // [NOBJ][2]

    region_kernel<<<dim3(NOBJ, SPLIT), 256, 0, stream>>>(
        pred_masks, gt_masks, pred_boxes, gt_boxes, pred_valid, gt_valid, acc, aux);
    finalize_kernel<<<1, 128, 0, stream>>>(acc, aux, out);
}